// Round 11
// baseline (279.936 us; speedup 1.0000x reference)
//
#include <hip/hip_runtime.h>

typedef __bf16 bf16x8 __attribute__((ext_vector_type(8)));
typedef __bf16 bf16x4 __attribute__((ext_vector_type(4)));
typedef float  f32x4  __attribute__((ext_vector_type(4)));

#define MFMA16(a,b,c) __builtin_amdgcn_mfma_f32_16x16x32_bf16((a),(b),(c),0,0,0)

constexpr int B_ = 256, T_ = 200, DM = 2048, DK = 128;
constexpr int VT_STRIDE = 208;      // Vt[b][v][t], t padded 200->208

// ws layout (bytes)
constexpr size_t OFF_W = 0;                       // Wcat bf16 [384][2048] = 1,572,864
constexpr size_t OFF_Q = 1572864;                 // Q bf16 [51200][128] = 13,107,200
constexpr size_t OFF_K = OFF_Q + 13107200;        // K bf16 [51200][128]
constexpr size_t OFF_V = OFF_K + 13107200;        // Vt bf16 [256][128][208] = 13,631,488

#define GLOAD_LDS16(G, L)                                                     \
  __builtin_amdgcn_global_load_lds(                                           \
      (const __attribute__((address_space(1))) void*)(G),                     \
      (__attribute__((address_space(3))) void*)(L), 16, 0, 0)

// ---------------- weight conversion: Wq|Wk|Wv fp32 -> Wcat bf16 [384][2048] ----------------
__global__ __launch_bounds__(256) void wconv_kernel(const float* __restrict__ Wq,
                                                    const float* __restrict__ Wk,
                                                    const float* __restrict__ Wv,
                                                    __bf16* __restrict__ Wcat) {
  int idx = (blockIdx.x * 256 + threadIdx.x) * 4;   // < 384*2048 = 786432
  int sel = idx >> 18;                              // /262144 -> 0,1,2
  const float* base = (sel == 0) ? Wq : (sel == 1) ? Wk : Wv;
  float4 f = *(const float4*)(base + (idx - (sel << 18)));
  bf16x4 o;
  o[0] = (__bf16)f.x; o[1] = (__bf16)f.y; o[2] = (__bf16)f.z; o[3] = (__bf16)f.w;
  *(bf16x4*)(Wcat + idx) = o;
}

// ---------------- projection GEMM: C[51200][384] = q(fp32->bf16) @ Wcat^T ----------------
// R10 geometry (128x128 tile, 256 thr, 2m x 2n waves, XCD-triplet job map) + BK=32 +
// ping-pong 32 KB LDS (3 blocks/CU) + COUNTED vmcnt (never 0 in steady state) +
// A reg-staged: fp32 global loads issued 2 steps early, cvt->ds_write bf16 AFTER compute
// (cvt off the MFMA critical path, once per element; A LDS traffic halved vs fp32 staging).
// B via global_load_lds, 1-step lead (Wcat L2-resident). Inner loop: 8 ds_read_b128 +
// 16 MFMA, zero cvt. Both-sides swizzle: phys_chunk = c ^ ((row>>1)&3) (A & B) -> 2-way.
__global__ __launch_bounds__(256) void proj_kernel(const float* __restrict__ q,
                                                   const __bf16* __restrict__ Wcat,
                                                   __bf16* __restrict__ Qo,
                                                   __bf16* __restrict__ Ko,
                                                   __bf16* __restrict__ Vt) {
  // buf0: A @0 (8KB), B @8192 (8KB); buf1: A @16384, B @24576. total 32 KB
  __shared__ alignas(16) char smem[32768];

  const int tid  = threadIdx.x;
  const int lane = tid & 63;
  const int w    = tid >> 6;
  const int wm   = w >> 1, wn = w & 1;
  const int lhi  = lane >> 4, llo = lane & 15;

  // XCD-grouped job mapping (1200 = 8 XCDs x 150 jobs; 150 % 3 == 0 so triplets never straddle)
  const int d  = blockIdx.x;
  const int jj = (d & 7) * 150 + (d >> 3);
  const int mp = jj / 3, nb = jj - mp * 3;
  const int m0 = mp * 128;
  const int col0 = nb * 128;

  f32x4 acc[4][4];
#pragma unroll
  for (int i = 0; i < 4; ++i)
#pragma unroll
    for (int j = 0; j < 4; ++j) acc[i][j] = {0.f, 0.f, 0.f, 0.f};

  // ---- A reg-stage mapping: thread -> row = tid>>1 (0..127), half = tid&1 (16 fp32) ----
  const int arow = tid >> 1, ahalf = tid & 1;
  const float* aptr = q + (size_t)(m0 + arow) * DM + ahalf * 16;
  // A LDS write offsets (bf16 row = 64B = 4 chunks; phys = c ^ ((row>>1)&3))
  const int aswz = (tid >> 2) & 3;
  const int aw0 = arow * 64 + (((ahalf * 2)     ^ aswz) << 4);
  const int aw1 = arow * 64 + (((ahalf * 2 + 1) ^ aswz) << 4);
  // ---- B staging: 2 rounds; slot=tid+256r -> row=(tid>>2)+64r, phys=tid&3,
  //      logical = (tid&3)^((row>>1)&3) = (tid&3)^((tid>>3)&3)  (round-invariant) ----
  const __bf16* bgbase = Wcat + (size_t)(col0 + (tid >> 2)) * DM
                              + (((tid & 3) ^ ((tid >> 3) & 3)) << 3);
  // ---- frag-read offsets: (row>>1)&3 == (llo>>1)&3 for all i/j (16-row steps) ----
  const int fswz = (llo >> 1) & 3;
  const int aro  = (wm * 64 + llo) * 64 + ((lhi ^ fswz) << 4);   // + i*1024
  const int bro  = (wn * 64 + llo) * 64 + ((lhi ^ fswz) << 4);   // + j*1024

  f32x4 r0a, r0b, r0c, r0d, r1a, r1b, r1c, r1d;   // two A reg sets (static names)

#define A_ISSUE(RA, RB, RC, RD, K0)                                           \
  { const float* p_ = aptr + (K0);                                            \
    RA = *(const f32x4*)(p_);      RB = *(const f32x4*)(p_ + 4);              \
    RC = *(const f32x4*)(p_ + 8);  RD = *(const f32x4*)(p_ + 12); }

#define B_ISSUE(BUFB, K0)                                                     \
  { char* lb_ = smem + 8192 + (BUFB) * 16384 + tid * 16;                      \
    GLOAD_LDS16(bgbase + (K0), lb_);                                          \
    GLOAD_LDS16(bgbase + (size_t)64 * DM + (K0), lb_ + 4096); }

#define A_PUB(RA, RB, RC, RD, BUFB)                                           \
  { char* la_ = smem + (BUFB) * 16384;                                        \
    bf16x8 p0, p1;                                                            \
    p0[0]=(__bf16)RA[0]; p0[1]=(__bf16)RA[1]; p0[2]=(__bf16)RA[2]; p0[3]=(__bf16)RA[3]; \
    p0[4]=(__bf16)RB[0]; p0[5]=(__bf16)RB[1]; p0[6]=(__bf16)RB[2]; p0[7]=(__bf16)RB[3]; \
    p1[0]=(__bf16)RC[0]; p1[1]=(__bf16)RC[1]; p1[2]=(__bf16)RC[2]; p1[3]=(__bf16)RC[3]; \
    p1[4]=(__bf16)RD[0]; p1[5]=(__bf16)RD[1]; p1[6]=(__bf16)RD[2]; p1[7]=(__bf16)RD[3]; \
    *(bf16x8*)(la_ + aw0) = p0;                                               \
    *(bf16x8*)(la_ + aw1) = p1; }

#define COMPUTE(BUFB)                                                         \
  { const char* la_ = smem + (BUFB) * 16384;                                  \
    const char* lb_ = la_ + 8192;                                             \
    bf16x8 af[4], bfr[4];                                                     \
    _Pragma("unroll")                                                         \
    for (int i = 0; i < 4; ++i) af[i]  = *(const bf16x8*)(la_ + aro + i * 1024); \
    _Pragma("unroll")                                                         \
    for (int j = 0; j < 4; ++j) bfr[j] = *(const bf16x8*)(lb_ + bro + j * 1024); \
    _Pragma("unroll")                                                         \
    for (int i = 0; i < 4; ++i)                                               \
      _Pragma("unroll")                                                       \
      for (int j = 0; j < 4; ++j) acc[i][j] = MFMA16(af[i], bfr[j], acc[i][j]); }

#define VMW(N)  asm volatile("s_waitcnt vmcnt(" #N ")" ::: "memory")
#define LGKM0() asm volatile("s_waitcnt lgkmcnt(0)" ::: "memory")
#define BAR()   __builtin_amdgcn_s_barrier()

  constexpr int NK = DM / 32;   // 64 K-steps
  // ---- prologue: A(0)->regs->LDS0, A(1)->regs, B(0)->LDS0 ----
  A_ISSUE(r0a, r0b, r0c, r0d, 0);
  A_ISSUE(r1a, r1b, r1c, r1d, 32);
  B_ISSUE(0, 0);
  A_PUB(r0a, r0b, r0c, r0d, 0);   // compiler waits A(0) regs
  VMW(0);                          // prologue-only full drain (B(0) landed)
  LGKM0();
  BAR();

  // ---- steady pairs: t = 0..61 ----
  for (int tp = 0; tp < 31; ++tp) {
    const int t0 = tp * 2;
    { // even t0: compute buf0
      B_ISSUE(1, (t0 + 1) * 32);
      A_ISSUE(r0a, r0b, r0c, r0d, (t0 + 2) * 32);
      VMW(10);                    // B(t0) landed; A(t0+1),B(t0+1),A(t0+2) in flight
      BAR();
      COMPUTE(0);
      A_PUB(r1a, r1b, r1c, r1d, 1);   // publish A(t0+1) (compiler counted-waits its regs)
      LGKM0();
      BAR();
    }
    { // odd t0+1: compute buf1
      B_ISSUE(0, (t0 + 2) * 32);
      A_ISSUE(r1a, r1b, r1c, r1d, (t0 + 3) * 32);
      VMW(10);
      BAR();
      COMPUTE(1);
      A_PUB(r0a, r0b, r0c, r0d, 0);
      LGKM0();
      BAR();
    }
  }
  { // t = 62 (even, buf0): no A(64) issue
    B_ISSUE(1, 63 * 32);
    VMW(6);                       // B(62) landed; A(63)+B(63) in flight
    BAR();
    COMPUTE(0);
    A_PUB(r1a, r1b, r1c, r1d, 1); // publish A(63)
    LGKM0();
    BAR();
  }
  { // t = 63 (odd, buf1): final
    VMW(0);
    BAR();
    COMPUTE(1);
  }
#undef A_ISSUE
#undef B_ISSUE
#undef A_PUB
#undef COMPUTE
#undef VMW
#undef LGKM0
#undef BAR

  // epilogue: nb selects destination (block-uniform branch)
  if (nb == 0) {
#pragma unroll
    for (int i = 0; i < 4; ++i)
#pragma unroll
      for (int r = 0; r < 4; ++r) {
        int row = m0 + wm * 64 + i * 16 + lhi * 4 + r;
#pragma unroll
        for (int j = 0; j < 4; ++j)
          Qo[(size_t)row * DK + wn * 64 + j * 16 + llo] = (__bf16)acc[i][j][r];
      }
  } else if (nb == 1) {
#pragma unroll
    for (int i = 0; i < 4; ++i)
#pragma unroll
      for (int r = 0; r < 4; ++r) {
        int row = m0 + wm * 64 + i * 16 + lhi * 4 + r;
#pragma unroll
        for (int j = 0; j < 4; ++j)
          Ko[(size_t)row * DK + wn * 64 + j * 16 + llo] = (__bf16)acc[i][j][r];
      }
  } else {
#pragma unroll
    for (int i = 0; i < 4; ++i)
#pragma unroll
      for (int r = 0; r < 4; ++r) {
        int row = m0 + wm * 64 + i * 16 + lhi * 4 + r;
        int b = row / 200;
        int t = row - b * 200;
#pragma unroll
        for (int j = 0; j < 4; ++j) {
          int col = wn * 64 + j * 16 + llo;
          Vt[((size_t)b * DK + col) * VT_STRIDE + t] = (__bf16)acc[i][j][r];
        }
      }
  }
}

// ---------------- attention: one WG per (batch, 64-query block), templated on block ----------------
template <int QB>
__global__ __launch_bounds__(256, 1) void attn_kernel(const __bf16* __restrict__ Qg,
                                                      const __bf16* __restrict__ Kg,
                                                      const __bf16* __restrict__ Vt,
                                                      const int* __restrict__ padm,
                                                      float* __restrict__ out) {
  constexpr int Q0     = QB * 64;
  constexpr int KMAX   = (Q0 + 64 < T_) ? (Q0 + 64) : T_;   // 64,128,192,200 (causal bound)
  constexpr int KTILES = (KMAX + 15) / 16;                  // 4,8,12,13
  constexpr int KCC    = (KMAX + 31) / 32;                  // 2,4,6,7
  constexpr int KT16   = KTILES * 16;                       // 64,128,192,208
  constexpr int KP     = KCC * 32;                          // 64,128,192,224
  constexpr int VS     = KP + 8;                            // padded stride (bank spread)

  __shared__ __bf16 sK[KT16][136];
  __shared__ __bf16 sV[128][VS];       // V^T: [v][t]
  __shared__ __bf16 sP[4][16][VS];     // per-wave P transpose buffer
  __shared__ float  sMask[KT16];

  const int tid  = threadIdx.x;
  const int lane = tid & 63;
  const int w    = tid >> 6;
  const int b    = blockIdx.x;
  const int lhi  = lane >> 4, llo = lane & 15;

  // additive key mask: 0 valid, -1e30 for pad / t>=KMAX
  for (int t = tid; t < KT16; t += 256) {
    float mv = -1e30f;
    if (t < KMAX && padm[b * T_ + t] == 0) mv = 0.0f;
    sMask[t] = mv;
  }
  // stage K rows [0, KT16) (rows >= T_ clamped; they get masked anyway)
  for (int cid = tid; cid < KT16 * 16; cid += 256) {
    int t = cid >> 4, c = (cid & 15) * 8;
    int tg = (t < T_) ? t : (T_ - 1);
    *(bf16x8*)&sK[t][c] = *(const bf16x8*)(Kg + ((size_t)b * T_ + tg) * DK + c);
  }
  // stage V^T: [128][KP), zeros beyond Vt's 208 columns
  {
    constexpr int NCH = KP / 8;
    for (int cid = tid; cid < 128 * NCH; cid += 256) {
      int v = cid / NCH, t0 = (cid % NCH) * 8;
      bf16x8 val;
      if (t0 < VT_STRIDE) {
        val = *(const bf16x8*)(Vt + ((size_t)b * DK + v) * VT_STRIDE + t0);
      } else {
#pragma unroll
        for (int jz = 0; jz < 8; ++jz) val[jz] = (__bf16)0.0f;
      }
      *(bf16x8*)&sV[v][t0] = val;
    }
  }
  // zero P pad columns [KT16, KP) (only QB==3: 208..224)
  if constexpr (KT16 < KP) {
    constexpr int NC = (KP - KT16) / 8;
    for (int idx = tid; idx < 4 * 16 * NC; idx += 256) {
      int ww = idx / (16 * NC);
      int rem = idx % (16 * NC);
      int row = rem / NC, cc = (rem % NC) * 8;
      bf16x8 z;
#pragma unroll
      for (int jz = 0; jz < 8; ++jz) z[jz] = (__bf16)0.0f;
      *(bf16x8*)&sP[ww][row][KT16 + cc] = z;
    }
  }
  __syncthreads();

  // Q fragments in registers (A-frag: row = llo, k-chunk = lhi)
  const int q0w = Q0 + w * 16;
  bf16x8 qf[4];
  {
    int qrow = q0w + llo;
    if (qrow > T_ - 1) qrow = T_ - 1;
    const __bf16* qp = Qg + ((size_t)b * T_ + qrow) * DK + lhi * 8;
#pragma unroll
    for (int kk = 0; kk < 4; ++kk) qf[kk] = *(const bf16x8*)(qp + kk * 32);
  }

  // scores: S[16q x KT16] per wave, kept in registers
  float sc[KTILES][4];
  const float scale = 0.022097086912079608f;   // 1/sqrt(2048)
#pragma unroll
  for (int tt = 0; tt < KTILES; ++tt) {
    f32x4 s = {0.f, 0.f, 0.f, 0.f};
    const __bf16* kp = &sK[tt * 16 + llo][lhi * 8];
#pragma unroll
    for (int kk = 0; kk < 4; ++kk) {
      bf16x8 kf = *(const bf16x8*)(kp + kk * 32);
      s = MFMA16(qf[kk], kf, s);
    }
    const int t = tt * 16 + llo;
    const float madd = sMask[t];
#pragma unroll
    for (int r = 0; r < 4; ++r) {
      int qq = q0w + lhi * 4 + r;               // C layout: row = lhi*4+r, col = llo
      float v = fmaf(s[r], scale, madd);
      sc[tt][r] = (t > qq) ? -1e30f : v;        // overwrite-style causal mask (NaN-safe)
    }
  }

  // row softmax: reduce across the 16-lane col group per accumulator row
#pragma unroll
  for (int r = 0; r < 4; ++r) {
    float mm = -3e38f;
#pragma unroll
    for (int tt = 0; tt < KTILES; ++tt) mm = fmaxf(mm, sc[tt][r]);
#pragma unroll
    for (int off = 1; off < 16; off <<= 1) mm = fmaxf(mm, __shfl_xor(mm, off));
    float ss = 0.f;
#pragma unroll
    for (int tt = 0; tt < KTILES; ++tt) { float e = __expf(sc[tt][r] - mm); sc[tt][r] = e; ss += e; }
#pragma unroll
    for (int off = 1; off < 16; off <<= 1) ss += __shfl_xor(ss, off);
    float inv = 1.0f / ss;
#pragma unroll
    for (int tt = 0; tt < KTILES; ++tt) sc[tt][r] *= inv;
  }

  // P -> LDS (transpose through memory for the PV A-fragment)
#pragma unroll
  for (int tt = 0; tt < KTILES; ++tt) {
    int t = tt * 16 + llo;
#pragma unroll
    for (int r = 0; r < 4; ++r) sP[w][lhi * 4 + r][t] = (__bf16)sc[tt][r];
  }
  __syncthreads();

  // PV: out[16q x 128v] = P[16 x KP] @ V[KP x 128]
  f32x4 oacc[8];
#pragma unroll
  for (int vt = 0; vt < 8; ++vt) oacc[vt] = {0.f, 0.f, 0.f, 0.f};
#pragma unroll
  for (int kc = 0; kc < KCC; ++kc) {
    bf16x8 pa = *(const bf16x8*)&sP[w][llo][kc * 32 + lhi * 8];
#pragma unroll
    for (int vt = 0; vt < 8; ++vt) {
      bf16x8 vb = *(const bf16x8*)&sV[vt * 16 + llo][kc * 32 + lhi * 8];
      oacc[vt] = MFMA16(pa, vb, oacc[vt]);
    }
  }

  // write fp32 output
#pragma unroll
  for (int vt = 0; vt < 8; ++vt) {
#pragma unroll
    for (int r = 0; r < 4; ++r) {
      int qq = q0w + lhi * 4 + r;
      if (qq < T_) out[((size_t)b * T_ + qq) * DK + vt * 16 + llo] = oacc[vt][r];
    }
  }
}

extern "C" void kernel_launch(void* const* d_in, const int* in_sizes, int n_in,
                              void* d_out, int out_size, void* d_ws, size_t ws_size,
                              hipStream_t stream) {
  const float* q    = (const float*)d_in[0];
  const int*   padm = (const int*)d_in[1];
  const float* Wq   = (const float*)d_in[2];
  const float* Wk   = (const float*)d_in[3];
  const float* Wv   = (const float*)d_in[4];
  float* out        = (float*)d_out;

  char* ws = (char*)d_ws;
  __bf16* Wcat = (__bf16*)(ws + OFF_W);
  __bf16* Qb   = (__bf16*)(ws + OFF_Q);
  __bf16* Kb   = (__bf16*)(ws + OFF_K);
  __bf16* Vtb  = (__bf16*)(ws + OFF_V);

  wconv_kernel<<<768, 256, 0, stream>>>(Wq, Wk, Wv, Wcat);
  proj_kernel<<<1200, 256, 0, stream>>>(q, Wcat, Qb, Kb, Vtb);
  attn_kernel<0><<<256, 256, 0, stream>>>(Qb, Kb, Vtb, padm, out);
  attn_kernel<1><<<256, 256, 0, stream>>>(Qb, Kb, Vtb, padm, out);
  attn_kernel<2><<<256, 256, 0, stream>>>(Qb, Kb, Vtb, padm, out);
  attn_kernel<3><<<256, 256, 0, stream>>>(Qb, Kb, Vtb, padm, out);
}

// Round 12
// 260.823 us; speedup vs baseline: 1.0733x; 1.0733x over previous
//
#include <hip/hip_runtime.h>

typedef __bf16 bf16x8 __attribute__((ext_vector_type(8)));
typedef __bf16 bf16x4 __attribute__((ext_vector_type(4)));
typedef float  f32x4  __attribute__((ext_vector_type(4)));

#define MFMA16(a,b,c) __builtin_amdgcn_mfma_f32_16x16x32_bf16((a),(b),(c),0,0,0)

constexpr int B_ = 256, T_ = 200, DM = 2048, DK = 128;
constexpr int VT_STRIDE = 208;      // Vt[b][v][t], t padded 200->208

// ws layout (bytes)
constexpr size_t OFF_W = 0;                       // Wcat bf16 [384][2048] = 1,572,864
constexpr size_t OFF_Q = 1572864;                 // Q bf16 [51200][128] = 13,107,200
constexpr size_t OFF_K = OFF_Q + 13107200;        // K bf16 [51200][128]
constexpr size_t OFF_V = OFF_K + 13107200;        // Vt bf16 [256][128][208] = 13,631,488

#define GLOAD_LDS16(G, L)                                                     \
  __builtin_amdgcn_global_load_lds(                                           \
      (const __attribute__((address_space(1))) void*)(G),                     \
      (__attribute__((address_space(3))) void*)(L), 16, 0, 0)

// ---------------- weight conversion: Wq|Wk|Wv fp32 -> Wcat bf16 [384][2048] ----------------
__global__ __launch_bounds__(256) void wconv_kernel(const float* __restrict__ Wq,
                                                    const float* __restrict__ Wk,
                                                    const float* __restrict__ Wv,
                                                    __bf16* __restrict__ Wcat) {
  int idx = (blockIdx.x * 256 + threadIdx.x) * 4;   // < 384*2048 = 786432
  int sel = idx >> 18;                              // /262144 -> 0,1,2
  const float* base = (sel == 0) ? Wq : (sel == 1) ? Wk : Wv;
  float4 f = *(const float4*)(base + (idx - (sel << 18)));
  bf16x4 o;
  o[0] = (__bf16)f.x; o[1] = (__bf16)f.y; o[2] = (__bf16)f.z; o[3] = (__bf16)f.w;
  *(bf16x4*)(Wcat + idx) = o;
}

// ---------------- projection GEMM: C[51200][384] = q(fp32->bf16) @ Wcat^T ----------------
// R11 geometry/swizzle kept (128x128 tile, 256 thr 2m x 2n, XCD-triplet map, BK=32,
// ping-pong 32 KB LDS, both-sides chunk swizzle c^((row>>1)&3)). Schedule fixed:
//  * 3 A-register sets rotating mod 3 -> A issued in body t is published in body t+2
//    (~1500 cy flight >= congested HBM latency; the compiler's vmcnt wait at the cvt
//    is then already satisfied).
//  * ONE barrier per body: VMW(4); s_barrier; B_ISSUE(buf^1); A_ISSUE; COMPUTE(buf);
//    sched_barrier; A_PUB(buf^1); lgkmcnt(0).  B_ISSUE after the barrier is WAR-safe
//    (barrier certifies all waves finished last generation's reads of buf^1), so the
//    second barrier of R11 is gone.  VMW(4) statically leaves only A(t+2) in flight.
__global__ __launch_bounds__(256) void proj_kernel(const float* __restrict__ q,
                                                   const __bf16* __restrict__ Wcat,
                                                   __bf16* __restrict__ Qo,
                                                   __bf16* __restrict__ Ko,
                                                   __bf16* __restrict__ Vt) {
  // buf0: A @0 (8KB), B @8192 (8KB); buf1: A @16384, B @24576. total 32 KB
  __shared__ alignas(16) char smem[32768];

  const int tid  = threadIdx.x;
  const int lane = tid & 63;
  const int w    = tid >> 6;
  const int wm   = w >> 1, wn = w & 1;
  const int lhi  = lane >> 4, llo = lane & 15;

  // XCD-grouped job mapping (1200 = 8 XCDs x 150 jobs; 150 % 3 == 0 so triplets never straddle)
  const int d  = blockIdx.x;
  const int jj = (d & 7) * 150 + (d >> 3);
  const int mp = jj / 3, nb = jj - mp * 3;
  const int m0 = mp * 128;
  const int col0 = nb * 128;

  f32x4 acc[4][4];
#pragma unroll
  for (int i = 0; i < 4; ++i)
#pragma unroll
    for (int j = 0; j < 4; ++j) acc[i][j] = {0.f, 0.f, 0.f, 0.f};

  // ---- A reg-stage mapping: thread -> row = tid>>1 (0..127), half = tid&1 (16 fp32) ----
  const int arow = tid >> 1, ahalf = tid & 1;
  const float* aptr = q + (size_t)(m0 + arow) * DM + ahalf * 16;
  // A LDS write offsets (bf16 row = 64B = 4 chunks; phys = c ^ ((row>>1)&3))
  const int aswz = (tid >> 2) & 3;
  const int aw0 = arow * 64 + (((ahalf * 2)     ^ aswz) << 4);
  const int aw1 = arow * 64 + (((ahalf * 2 + 1) ^ aswz) << 4);
  // ---- B staging: 2 rounds; slot=tid+256r -> row=(tid>>2)+64r, phys=tid&3,
  //      logical = (tid&3)^((row>>1)&3) = (tid&3)^((tid>>3)&3)  (round-invariant) ----
  const __bf16* bgbase = Wcat + (size_t)(col0 + (tid >> 2)) * DM
                              + (((tid & 3) ^ ((tid >> 3) & 3)) << 3);
  // ---- frag-read offsets: (row>>1)&3 == (llo>>1)&3 for all i/j (16-row steps) ----
  const int fswz = (llo >> 1) & 3;
  const int aro  = (wm * 64 + llo) * 64 + ((lhi ^ fswz) << 4);   // + i*1024
  const int bro  = (wn * 64 + llo) * 64 + ((lhi ^ fswz) << 4);   // + j*1024

  // three A register sets (static names, rule #20)
  f32x4 s0a, s0b, s0c, s0d, s1a, s1b, s1c, s1d, s2a, s2b, s2c, s2d;

#define A_ISSUE(RA, RB, RC, RD, K0)                                           \
  { const float* p_ = aptr + (K0);                                            \
    RA = *(const f32x4*)(p_);      RB = *(const f32x4*)(p_ + 4);              \
    RC = *(const f32x4*)(p_ + 8);  RD = *(const f32x4*)(p_ + 12); }

#define B_ISSUE(BUFB, K0)                                                     \
  { char* lb_ = smem + 8192 + (BUFB) * 16384 + tid * 16;                      \
    GLOAD_LDS16(bgbase + (K0), lb_);                                          \
    GLOAD_LDS16(bgbase + (size_t)64 * DM + (K0), lb_ + 4096); }

#define A_PUB(RA, RB, RC, RD, BUFB)                                           \
  { char* la_ = smem + (BUFB) * 16384;                                        \
    bf16x8 p0, p1;                                                            \
    p0[0]=(__bf16)RA[0]; p0[1]=(__bf16)RA[1]; p0[2]=(__bf16)RA[2]; p0[3]=(__bf16)RA[3]; \
    p0[4]=(__bf16)RB[0]; p0[5]=(__bf16)RB[1]; p0[6]=(__bf16)RB[2]; p0[7]=(__bf16)RB[3]; \
    p1[0]=(__bf16)RC[0]; p1[1]=(__bf16)RC[1]; p1[2]=(__bf16)RC[2]; p1[3]=(__bf16)RC[3]; \
    p1[4]=(__bf16)RD[0]; p1[5]=(__bf16)RD[1]; p1[6]=(__bf16)RD[2]; p1[7]=(__bf16)RD[3]; \
    *(bf16x8*)(la_ + aw0) = p0;                                               \
    *(bf16x8*)(la_ + aw1) = p1; }

#define COMPUTE(BUFB)                                                         \
  { const char* la_ = smem + (BUFB) * 16384;                                  \
    const char* lb_ = la_ + 8192;                                             \
    bf16x8 af[4], bfr[4];                                                     \
    _Pragma("unroll")                                                         \
    for (int i = 0; i < 4; ++i) af[i]  = *(const bf16x8*)(la_ + aro + i * 1024); \
    _Pragma("unroll")                                                         \
    for (int j = 0; j < 4; ++j) bfr[j] = *(const bf16x8*)(lb_ + bro + j * 1024); \
    _Pragma("unroll")                                                         \
    for (int i = 0; i < 4; ++i)                                               \
      _Pragma("unroll")                                                       \
      for (int j = 0; j < 4; ++j) acc[i][j] = MFMA16(af[i], bfr[j], acc[i][j]); }

#define VMW(N)   asm volatile("s_waitcnt vmcnt(" #N ")" ::: "memory")
#define LGKM0()  asm volatile("s_waitcnt lgkmcnt(0)" ::: "memory")
#define BARF()   { __builtin_amdgcn_s_barrier(); asm volatile("" ::: "memory"); }
#define SCHED0() __builtin_amdgcn_sched_barrier(0)

  // BODY(T): compute buf = T&1; publish set holding A(T+1) into buf^1; issue A(T+3)
  // into the just-freed set; stage B(T+1) into buf^1.  VMW(4): outstanding entering =
  // A(T+1)[4] (t-2), B(T)[2] (t-1), A(T+2)[4] (t-1); leave newest 4 = A(T+2).
#define BODY(BUF, PA, PB, PC, PD, IA, IB, IC, ID, T)                          \
  {                                                                           \
    VMW(4);                                                                   \
    BARF();                                                                   \
    B_ISSUE((BUF) ^ 1, ((T) + 1) * 32);                                       \
    A_ISSUE(IA, IB, IC, ID, ((T) + 3) * 32);                                  \
    COMPUTE(BUF);                                                             \
    SCHED0();                                                                 \
    A_PUB(PA, PB, PC, PD, (BUF) ^ 1);                                         \
    LGKM0();                                                                  \
  }

  // ---- prologue: sets s0<-A(0), s1<-A(1), s2<-A(2); B(0)->buf0; publish A(0) ----
  A_ISSUE(s0a, s0b, s0c, s0d, 0);
  A_ISSUE(s1a, s1b, s1c, s1d, 32);
  A_ISSUE(s2a, s2b, s2c, s2d, 64);
  B_ISSUE(0, 0);
  A_PUB(s0a, s0b, s0c, s0d, 0);
  VMW(0);          // prologue-only full drain (B(0), A(1), A(2) landed)
  LGKM0();

  // ---- main: t = 0..59 as 10 x 6-body pattern, then peel t = 60 ----
  for (int tp = 0; tp < 10; ++tp) {
    const int t0 = tp * 6;
    BODY(0, s1a,s1b,s1c,s1d, s0a,s0b,s0c,s0d, t0 + 0);
    BODY(1, s2a,s2b,s2c,s2d, s1a,s1b,s1c,s1d, t0 + 1);
    BODY(0, s0a,s0b,s0c,s0d, s2a,s2b,s2c,s2d, t0 + 2);
    BODY(1, s1a,s1b,s1c,s1d, s0a,s0b,s0c,s0d, t0 + 3);
    BODY(0, s2a,s2b,s2c,s2d, s1a,s1b,s1c,s1d, t0 + 4);
    BODY(1, s0a,s0b,s0c,s0d, s2a,s2b,s2c,s2d, t0 + 5);
  }
  BODY(0, s1a,s1b,s1c,s1d, s0a,s0b,s0c,s0d, 60);   // issues A(63), B(61)
  { // t = 61: compute buf1, publish A(62), stage B(62); VMW(4) leaves A(63)
    VMW(4);
    BARF();
    B_ISSUE(0, 62 * 32);
    COMPUTE(1);
    SCHED0();
    A_PUB(s2a, s2b, s2c, s2d, 0);
    LGKM0();
  }
  { // t = 62: compute buf0, publish A(63), stage B(63); B(62) is newest -> VMW(0)
    VMW(0);
    BARF();
    B_ISSUE(1, 63 * 32);
    COMPUTE(0);
    SCHED0();
    A_PUB(s0a, s0b, s0c, s0d, 1);
    LGKM0();
  }
  { // t = 63: final
    VMW(0);
    BARF();
    COMPUTE(1);
  }
#undef A_ISSUE
#undef B_ISSUE
#undef A_PUB
#undef COMPUTE
#undef VMW
#undef LGKM0
#undef BARF
#undef SCHED0
#undef BODY

  // epilogue: nb selects destination (block-uniform branch)
  if (nb == 0) {
#pragma unroll
    for (int i = 0; i < 4; ++i)
#pragma unroll
      for (int r = 0; r < 4; ++r) {
        int row = m0 + wm * 64 + i * 16 + lhi * 4 + r;
#pragma unroll
        for (int j = 0; j < 4; ++j)
          Qo[(size_t)row * DK + wn * 64 + j * 16 + llo] = (__bf16)acc[i][j][r];
      }
  } else if (nb == 1) {
#pragma unroll
    for (int i = 0; i < 4; ++i)
#pragma unroll
      for (int r = 0; r < 4; ++r) {
        int row = m0 + wm * 64 + i * 16 + lhi * 4 + r;
#pragma unroll
        for (int j = 0; j < 4; ++j)
          Ko[(size_t)row * DK + wn * 64 + j * 16 + llo] = (__bf16)acc[i][j][r];
      }
  } else {
#pragma unroll
    for (int i = 0; i < 4; ++i)
#pragma unroll
      for (int r = 0; r < 4; ++r) {
        int row = m0 + wm * 64 + i * 16 + lhi * 4 + r;
        int b = row / 200;
        int t = row - b * 200;
#pragma unroll
        for (int j = 0; j < 4; ++j) {
          int col = wn * 64 + j * 16 + llo;
          Vt[((size_t)b * DK + col) * VT_STRIDE + t] = (__bf16)acc[i][j][r];
        }
      }
  }
}

// ---------------- attention: one WG per (batch, 64-query block), templated on block ----------------
template <int QB>
__global__ __launch_bounds__(256, 1) void attn_kernel(const __bf16* __restrict__ Qg,
                                                      const __bf16* __restrict__ Kg,
                                                      const __bf16* __restrict__ Vt,
                                                      const int* __restrict__ padm,
                                                      float* __restrict__ out) {
  constexpr int Q0     = QB * 64;
  constexpr int KMAX   = (Q0 + 64 < T_) ? (Q0 + 64) : T_;   // 64,128,192,200 (causal bound)
  constexpr int KTILES = (KMAX + 15) / 16;                  // 4,8,12,13
  constexpr int KCC    = (KMAX + 31) / 32;                  // 2,4,6,7
  constexpr int KT16   = KTILES * 16;                       // 64,128,192,208
  constexpr int KP     = KCC * 32;                          // 64,128,192,224
  constexpr int VS     = KP + 8;                            // padded stride (bank spread)

  __shared__ __bf16 sK[KT16][136];
  __shared__ __bf16 sV[128][VS];       // V^T: [v][t]
  __shared__ __bf16 sP[4][16][VS];     // per-wave P transpose buffer
  __shared__ float  sMask[KT16];

  const int tid  = threadIdx.x;
  const int lane = tid & 63;
  const int w    = tid >> 6;
  const int b    = blockIdx.x;
  const int lhi  = lane >> 4, llo = lane & 15;

  // additive key mask: 0 valid, -1e30 for pad / t>=KMAX
  for (int t = tid; t < KT16; t += 256) {
    float mv = -1e30f;
    if (t < KMAX && padm[b * T_ + t] == 0) mv = 0.0f;
    sMask[t] = mv;
  }
  // stage K rows [0, KT16) (rows >= T_ clamped; they get masked anyway)
  for (int cid = tid; cid < KT16 * 16; cid += 256) {
    int t = cid >> 4, c = (cid & 15) * 8;
    int tg = (t < T_) ? t : (T_ - 1);
    *(bf16x8*)&sK[t][c] = *(const bf16x8*)(Kg + ((size_t)b * T_ + tg) * DK + c);
  }
  // stage V^T: [128][KP), zeros beyond Vt's 208 columns
  {
    constexpr int NCH = KP / 8;
    for (int cid = tid; cid < 128 * NCH; cid += 256) {
      int v = cid / NCH, t0 = (cid % NCH) * 8;
      bf16x8 val;
      if (t0 < VT_STRIDE) {
        val = *(const bf16x8*)(Vt + ((size_t)b * DK + v) * VT_STRIDE + t0);
      } else {
#pragma unroll
        for (int jz = 0; jz < 8; ++jz) val[jz] = (__bf16)0.0f;
      }
      *(bf16x8*)&sV[v][t0] = val;
    }
  }
  // zero P pad columns [KT16, KP) (only QB==3: 208..224)
  if constexpr (KT16 < KP) {
    constexpr int NC = (KP - KT16) / 8;
    for (int idx = tid; idx < 4 * 16 * NC; idx += 256) {
      int ww = idx / (16 * NC);
      int rem = idx % (16 * NC);
      int row = rem / NC, cc = (rem % NC) * 8;
      bf16x8 z;
#pragma unroll
      for (int jz = 0; jz < 8; ++jz) z[jz] = (__bf16)0.0f;
      *(bf16x8*)&sP[ww][row][KT16 + cc] = z;
    }
  }
  __syncthreads();

  // Q fragments in registers (A-frag: row = llo, k-chunk = lhi)
  const int q0w = Q0 + w * 16;
  bf16x8 qf[4];
  {
    int qrow = q0w + llo;
    if (qrow > T_ - 1) qrow = T_ - 1;
    const __bf16* qp = Qg + ((size_t)b * T_ + qrow) * DK + lhi * 8;
#pragma unroll
    for (int kk = 0; kk < 4; ++kk) qf[kk] = *(const bf16x8*)(qp + kk * 32);
  }

  // scores: S[16q x KT16] per wave, kept in registers
  float sc[KTILES][4];
  const float scale = 0.022097086912079608f;   // 1/sqrt(2048)
#pragma unroll
  for (int tt = 0; tt < KTILES; ++tt) {
    f32x4 s = {0.f, 0.f, 0.f, 0.f};
    const __bf16* kp = &sK[tt * 16 + llo][lhi * 8];
#pragma unroll
    for (int kk = 0; kk < 4; ++kk) {
      bf16x8 kf = *(const bf16x8*)(kp + kk * 32);
      s = MFMA16(qf[kk], kf, s);
    }
    const int t = tt * 16 + llo;
    const float madd = sMask[t];
#pragma unroll
    for (int r = 0; r < 4; ++r) {
      int qq = q0w + lhi * 4 + r;               // C layout: row = lhi*4+r, col = llo
      float v = fmaf(s[r], scale, madd);
      sc[tt][r] = (t > qq) ? -1e30f : v;        // overwrite-style causal mask (NaN-safe)
    }
  }

  // row softmax: reduce across the 16-lane col group per accumulator row
#pragma unroll
  for (int r = 0; r < 4; ++r) {
    float mm = -3e38f;
#pragma unroll
    for (int tt = 0; tt < KTILES; ++tt) mm = fmaxf(mm, sc[tt][r]);
#pragma unroll
    for (int off = 1; off < 16; off <<= 1) mm = fmaxf(mm, __shfl_xor(mm, off));
    float ss = 0.f;
#pragma unroll
    for (int tt = 0; tt < KTILES; ++tt) { float e = __expf(sc[tt][r] - mm); sc[tt][r] = e; ss += e; }
#pragma unroll
    for (int off = 1; off < 16; off <<= 1) ss += __shfl_xor(ss, off);
    float inv = 1.0f / ss;
#pragma unroll
    for (int tt = 0; tt < KTILES; ++tt) sc[tt][r] *= inv;
  }

  // P -> LDS (transpose through memory for the PV A-fragment)
#pragma unroll
  for (int tt = 0; tt < KTILES; ++tt) {
    int t = tt * 16 + llo;
#pragma unroll
    for (int r = 0; r < 4; ++r) sP[w][lhi * 4 + r][t] = (__bf16)sc[tt][r];
  }
  __syncthreads();

  // PV: out[16q x 128v] = P[16 x KP] @ V[KP x 128]
  f32x4 oacc[8];
#pragma unroll
  for (int vt = 0; vt < 8; ++vt) oacc[vt] = {0.f, 0.f, 0.f, 0.f};
#pragma unroll
  for (int kc = 0; kc < KCC; ++kc) {
    bf16x8 pa = *(const bf16x8*)&sP[w][llo][kc * 32 + lhi * 8];
#pragma unroll
    for (int vt = 0; vt < 8; ++vt) {
      bf16x8 vb = *(const bf16x8*)&sV[vt * 16 + llo][kc * 32 + lhi * 8];
      oacc[vt] = MFMA16(pa, vb, oacc[vt]);
    }
  }

  // write fp32 output
#pragma unroll
  for (int vt = 0; vt < 8; ++vt) {
#pragma unroll
    for (int r = 0; r < 4; ++r) {
      int qq = q0w + lhi * 4 + r;
      if (qq < T_) out[((size_t)b * T_ + qq) * DK + vt * 16 + llo] = oacc[vt][r];
    }
  }
}

extern "C" void kernel_launch(void* const* d_in, const int* in_sizes, int n_in,
                              void* d_out, int out_size, void* d_ws, size_t ws_size,
                              hipStream_t stream) {
  const float* q    = (const float*)d_in[0];
  const int*   padm = (const int*)d_in[1];
  const float* Wq   = (const float*)d_in[2];
  const float* Wk   = (const float*)d_in[3];
  const float* Wv   = (const float*)d_in[4];
  float* out        = (float*)d_out;

  char* ws = (char*)d_ws;
  __bf16* Wcat = (__bf16*)(ws + OFF_W);
  __bf16* Qb   = (__bf16*)(ws + OFF_Q);
  __bf16* Kb   = (__bf16*)(ws + OFF_K);
  __bf16* Vtb  = (__bf16*)(ws + OFF_V);

  wconv_kernel<<<768, 256, 0, stream>>>(Wq, Wk, Wv, Wcat);
  proj_kernel<<<1200, 256, 0, stream>>>(q, Wcat, Qb, Kb, Vtb);
  attn_kernel<0><<<256, 256, 0, stream>>>(Qb, Kb, Vtb, padm, out);
  attn_kernel<1><<<256, 256, 0, stream>>>(Qb, Kb, Vtb, padm, out);
  attn_kernel<2><<<256, 256, 0, stream>>>(Qb, Kb, Vtb, padm, out);
  attn_kernel<3><<<256, 256, 0, stream>>>(Qb, Kb, Vtb, padm, out);
}

// Round 13
// 247.137 us; speedup vs baseline: 1.1327x; 1.0554x over previous
//
#include <hip/hip_runtime.h>

typedef __bf16 bf16x8 __attribute__((ext_vector_type(8)));
typedef __bf16 bf16x4 __attribute__((ext_vector_type(4)));
typedef float  f32x4  __attribute__((ext_vector_type(4)));

#define MFMA16(a,b,c) __builtin_amdgcn_mfma_f32_16x16x32_bf16((a),(b),(c),0,0,0)

constexpr int B_ = 256, T_ = 200, DM = 2048, DK = 128;
constexpr int VT_STRIDE = 208;      // Vt[b][v][t], t padded 200->208

// ws layout (bytes)
constexpr size_t OFF_W = 0;                       // Wcat bf16 [384][2048] = 1,572,864
constexpr size_t OFF_Q = 1572864;                 // Q bf16 [51200][128] = 13,107,200
constexpr size_t OFF_K = OFF_Q + 13107200;        // K bf16 [51200][128]
constexpr size_t OFF_V = OFF_K + 13107200;        // Vt bf16 [256][128][208] = 13,631,488

#define GLOAD_LDS16(G, L)                                                     \
  __builtin_amdgcn_global_load_lds(                                           \
      (const __attribute__((address_space(1))) void*)(G),                     \
      (__attribute__((address_space(3))) void*)(L), 16, 0, 0)

// ---------------- weight conversion: Wq|Wk|Wv fp32 -> Wcat bf16 [384][2048] ----------------
__global__ __launch_bounds__(256) void wconv_kernel(const float* __restrict__ Wq,
                                                    const float* __restrict__ Wk,
                                                    const float* __restrict__ Wv,
                                                    __bf16* __restrict__ Wcat) {
  int idx = (blockIdx.x * 256 + threadIdx.x) * 4;   // < 384*2048 = 786432
  int sel = idx >> 18;                              // /262144 -> 0,1,2
  const float* base = (sel == 0) ? Wq : (sel == 1) ? Wk : Wv;
  float4 f = *(const float4*)(base + (idx - (sel << 18)));
  bf16x4 o;
  o[0] = (__bf16)f.x; o[1] = (__bf16)f.y; o[2] = (__bf16)f.z; o[3] = (__bf16)f.w;
  *(bf16x4*)(Wcat + idx) = o;
}

// ---------------- projection GEMM: C[51200][384] = q(fp32->bf16) @ Wcat^T ----------------
// TLP-first: 128x128 tile, BK=64, 512 threads = 8 waves (2m x 4n, wave tile 64x32,
// acc = 32 AGPR). ~110-125 unified regs -> 4 waves/SIMD; 48 KB single-buffer LDS ->
// 2 blocks/CU = 16 waves/CU (2.7x the TLP of R6-R12's designs; m114 cross-wave overlap
// is what hides the stage drains). m97 2-barrier loop (proven best so far, R10).
// Staging COALESCED (fixed from R6-R12): 16 lanes cover one full 256-B fp32 A-row
// (4 rows per instr, lines fully covered); 8 lanes per 128-B B-row. Both-sides XOR
// swizzle (chunk ^ row&15 for A, ^ row&7 for B), round-invariant per thread; the XOR
// only permutes within a row so coalescing is preserved. Frag reads 2-way (free).
// XCD-triplet job map: the 3 N-blocks (Q/K/Vt) of an M-panel run adjacently on one
// XCD -> A K-slices served from its L2/L3 (q HBM-read ~once; R10-proven).
__global__ __launch_bounds__(512) void proj_kernel(const float* __restrict__ q,
                                                   const __bf16* __restrict__ Wcat,
                                                   __bf16* __restrict__ Qo,
                                                   __bf16* __restrict__ Ko,
                                                   __bf16* __restrict__ Vt) {
  __shared__ alignas(16) char smem[49152];   // A fp32 [128][64] @0 (32 KB), B bf16 [128][64] @32768 (16 KB)

  const int tid  = threadIdx.x;
  const int lane = tid & 63;
  const int w    = tid >> 6;
  const int wm   = w >> 2, wn = w & 3;       // 2 waves over M, 4 over N
  const int lhi  = lane >> 4, llo = lane & 15;

  // XCD-grouped job mapping (1200 = 8 XCDs x 150 jobs; 150 % 3 == 0 -> triplets never straddle)
  const int d  = blockIdx.x;
  const int jj = (d & 7) * 150 + (d >> 3);
  const int mp = jj / 3, nb = jj - mp * 3;
  const int m0 = mp * 128;
  const int col0 = nb * 128;

  f32x4 acc[4][2];
#pragma unroll
  for (int i = 0; i < 4; ++i)
#pragma unroll
    for (int j = 0; j < 2; ++j) acc[i][j] = {0.f, 0.f, 0.f, 0.f};

  // A staging: 4 rounds of 32 rows; row = (tid>>4) + 32r (16 lanes cover the full
  // 256-B fp32 row); src chunk = (tid&15) ^ ((tid>>4)&15)  (round-invariant XOR,
  // permutes within the row -> coalescing intact)
  const float* agbase = q + (size_t)(m0 + (tid >> 4)) * DM
                          + (((tid & 15) ^ ((tid >> 4) & 15)) << 2);
  // B staging: 2 rounds of 64 rows; row = (tid>>3) + 64r (8 lanes cover the 128-B row);
  // src chunk = (tid&7) ^ ((tid>>3)&7)
  const __bf16* bgbase = Wcat + (size_t)(col0 + (tid >> 3)) * DM
                              + (((tid & 7) ^ ((tid >> 3) & 7)) << 3);

  constexpr int NK = DM / 64;   // 32 K-steps
  for (int t = 0; t < NK; ++t) {
    const int k0 = t * 64;
#pragma unroll
    for (int r = 0; r < 4; ++r)
      GLOAD_LDS16(agbase + (size_t)r * 32 * DM + k0, smem + tid * 16 + r * 8192);
#pragma unroll
    for (int r = 0; r < 2; ++r)
      GLOAD_LDS16(bgbase + (size_t)r * 64 * DM + k0, smem + 32768 + tid * 16 + r * 8192);
    __syncthreads();           // tile t visible

#pragma unroll
    for (int kk = 0; kk < 2; ++kk) {
      bf16x8 af[4];
#pragma unroll
      for (int i = 0; i < 4; ++i) {
        const int row = wm * 64 + i * 16 + llo;          // row & 15 == llo
        const int c0 = kk * 8 + lhi * 2;
        f32x4 u = *(const f32x4*)(smem + row * 256 + (((c0 ^ llo) & 15) << 4));
        f32x4 v = *(const f32x4*)(smem + row * 256 + ((((c0 + 1) ^ llo) & 15) << 4));
        af[i][0]=(__bf16)u[0]; af[i][1]=(__bf16)u[1]; af[i][2]=(__bf16)u[2]; af[i][3]=(__bf16)u[3];
        af[i][4]=(__bf16)v[0]; af[i][5]=(__bf16)v[1]; af[i][6]=(__bf16)v[2]; af[i][7]=(__bf16)v[3];
      }
      bf16x8 bfr[2];
#pragma unroll
      for (int j = 0; j < 2; ++j) {
        const int row = wn * 32 + j * 16 + llo;          // row & 7 == llo & 7
        const int c = kk * 4 + lhi;
        bfr[j] = *(const bf16x8*)(smem + 32768 + row * 128 + (((c ^ (llo & 7)) & 7) << 4));
      }
#pragma unroll
      for (int i = 0; i < 4; ++i)
#pragma unroll
        for (int j = 0; j < 2; ++j) acc[i][j] = MFMA16(af[i], bfr[j], acc[i][j]);
    }
    if (t + 1 < NK) __syncthreads();   // protect single buffer before next stage
  }

  // epilogue: nb selects destination (block-uniform branch)
  if (nb == 0) {
#pragma unroll
    for (int i = 0; i < 4; ++i)
#pragma unroll
      for (int r = 0; r < 4; ++r) {
        int row = m0 + wm * 64 + i * 16 + lhi * 4 + r;
#pragma unroll
        for (int j = 0; j < 2; ++j)
          Qo[(size_t)row * DK + wn * 32 + j * 16 + llo] = (__bf16)acc[i][j][r];
      }
  } else if (nb == 1) {
#pragma unroll
    for (int i = 0; i < 4; ++i)
#pragma unroll
      for (int r = 0; r < 4; ++r) {
        int row = m0 + wm * 64 + i * 16 + lhi * 4 + r;
#pragma unroll
        for (int j = 0; j < 2; ++j)
          Ko[(size_t)row * DK + wn * 32 + j * 16 + llo] = (__bf16)acc[i][j][r];
      }
  } else {
#pragma unroll
    for (int i = 0; i < 4; ++i)
#pragma unroll
      for (int r = 0; r < 4; ++r) {
        int row = m0 + wm * 64 + i * 16 + lhi * 4 + r;
        int b = row / 200;
        int t = row - b * 200;
#pragma unroll
        for (int j = 0; j < 2; ++j) {
          int col = wn * 32 + j * 16 + llo;
          Vt[((size_t)b * DK + col) * VT_STRIDE + t] = (__bf16)acc[i][j][r];
        }
      }
  }
}

// ---------------- attention: one WG per (batch, 64-query block), templated on block ----------------
template <int QB>
__global__ __launch_bounds__(256, 1) void attn_kernel(const __bf16* __restrict__ Qg,
                                                      const __bf16* __restrict__ Kg,
                                                      const __bf16* __restrict__ Vt,
                                                      const int* __restrict__ padm,
                                                      float* __restrict__ out) {
  constexpr int Q0     = QB * 64;
  constexpr int KMAX   = (Q0 + 64 < T_) ? (Q0 + 64) : T_;   // 64,128,192,200 (causal bound)
  constexpr int KTILES = (KMAX + 15) / 16;                  // 4,8,12,13
  constexpr int KCC    = (KMAX + 31) / 32;                  // 2,4,6,7
  constexpr int KT16   = KTILES * 16;                       // 64,128,192,208
  constexpr int KP     = KCC * 32;                          // 64,128,192,224
  constexpr int VS     = KP + 8;                            // padded stride (bank spread)

  __shared__ __bf16 sK[KT16][136];
  __shared__ __bf16 sV[128][VS];       // V^T: [v][t]
  __shared__ __bf16 sP[4][16][VS];     // per-wave P transpose buffer
  __shared__ float  sMask[KT16];

  const int tid  = threadIdx.x;
  const int lane = tid & 63;
  const int w    = tid >> 6;
  const int b    = blockIdx.x;
  const int lhi  = lane >> 4, llo = lane & 15;

  // additive key mask: 0 valid, -1e30 for pad / t>=KMAX
  for (int t = tid; t < KT16; t += 256) {
    float mv = -1e30f;
    if (t < KMAX && padm[b * T_ + t] == 0) mv = 0.0f;
    sMask[t] = mv;
  }
  // stage K rows [0, KT16) (rows >= T_ clamped; they get masked anyway)
  for (int cid = tid; cid < KT16 * 16; cid += 256) {
    int t = cid >> 4, c = (cid & 15) * 8;
    int tg = (t < T_) ? t : (T_ - 1);
    *(bf16x8*)&sK[t][c] = *(const bf16x8*)(Kg + ((size_t)b * T_ + tg) * DK + c);
  }
  // stage V^T: [128][KP), zeros beyond Vt's 208 columns
  {
    constexpr int NCH = KP / 8;
    for (int cid = tid; cid < 128 * NCH; cid += 256) {
      int v = cid / NCH, t0 = (cid % NCH) * 8;
      bf16x8 val;
      if (t0 < VT_STRIDE) {
        val = *(const bf16x8*)(Vt + ((size_t)b * DK + v) * VT_STRIDE + t0);
      } else {
#pragma unroll
        for (int jz = 0; jz < 8; ++jz) val[jz] = (__bf16)0.0f;
      }
      *(bf16x8*)&sV[v][t0] = val;
    }
  }
  // zero P pad columns [KT16, KP) (only QB==3: 208..224)
  if constexpr (KT16 < KP) {
    constexpr int NC = (KP - KT16) / 8;
    for (int idx = tid; idx < 4 * 16 * NC; idx += 256) {
      int ww = idx / (16 * NC);
      int rem = idx % (16 * NC);
      int row = rem / NC, cc = (rem % NC) * 8;
      bf16x8 z;
#pragma unroll
      for (int jz = 0; jz < 8; ++jz) z[jz] = (__bf16)0.0f;
      *(bf16x8*)&sP[ww][row][KT16 + cc] = z;
    }
  }
  __syncthreads();

  // Q fragments in registers (A-frag: row = llo, k-chunk = lhi)
  const int q0w = Q0 + w * 16;
  bf16x8 qf[4];
  {
    int qrow = q0w + llo;
    if (qrow > T_ - 1) qrow = T_ - 1;
    const __bf16* qp = Qg + ((size_t)b * T_ + qrow) * DK + lhi * 8;
#pragma unroll
    for (int kk = 0; kk < 4; ++kk) qf[kk] = *(const bf16x8*)(qp + kk * 32);
  }

  // scores: S[16q x KT16] per wave, kept in registers
  float sc[KTILES][4];
  const float scale = 0.022097086912079608f;   // 1/sqrt(2048)
#pragma unroll
  for (int tt = 0; tt < KTILES; ++tt) {
    f32x4 s = {0.f, 0.f, 0.f, 0.f};
    const __bf16* kp = &sK[tt * 16 + llo][lhi * 8];
#pragma unroll
    for (int kk = 0; kk < 4; ++kk) {
      bf16x8 kf = *(const bf16x8*)(kp + kk * 32);
      s = MFMA16(qf[kk], kf, s);
    }
    const int t = tt * 16 + llo;
    const float madd = sMask[t];
#pragma unroll
    for (int r = 0; r < 4; ++r) {
      int qq = q0w + lhi * 4 + r;               // C layout: row = lhi*4+r, col = llo
      float v = fmaf(s[r], scale, madd);
      sc[tt][r] = (t > qq) ? -1e30f : v;        // overwrite-style causal mask (NaN-safe)
    }
  }

  // row softmax: reduce across the 16-lane col group per accumulator row
#pragma unroll
  for (int r = 0; r < 4; ++r) {
    float mm = -3e38f;
#pragma unroll
    for (int tt = 0; tt < KTILES; ++tt) mm = fmaxf(mm, sc[tt][r]);
#pragma unroll
    for (int off = 1; off < 16; off <<= 1) mm = fmaxf(mm, __shfl_xor(mm, off));
    float ss = 0.f;
#pragma unroll
    for (int tt = 0; tt < KTILES; ++tt) { float e = __expf(sc[tt][r] - mm); sc[tt][r] = e; ss += e; }
#pragma unroll
    for (int off = 1; off < 16; off <<= 1) ss += __shfl_xor(ss, off);
    float inv = 1.0f / ss;
#pragma unroll
    for (int tt = 0; tt < KTILES; ++tt) sc[tt][r] *= inv;
  }

  // P -> LDS (transpose through memory for the PV A-fragment)
#pragma unroll
  for (int tt = 0; tt < KTILES; ++tt) {
    int t = tt * 16 + llo;
#pragma unroll
    for (int r = 0; r < 4; ++r) sP[w][lhi * 4 + r][t] = (__bf16)sc[tt][r];
  }
  __syncthreads();

  // PV: out[16q x 128v] = P[16 x KP] @ V[KP x 128]
  f32x4 oacc[8];
#pragma unroll
  for (int vt = 0; vt < 8; ++vt) oacc[vt] = {0.f, 0.f, 0.f, 0.f};
#pragma unroll
  for (int kc = 0; kc < KCC; ++kc) {
    bf16x8 pa = *(const bf16x8*)&sP[w][llo][kc * 32 + lhi * 8];
#pragma unroll
    for (int vt = 0; vt < 8; ++vt) {
      bf16x8 vb = *(const bf16x8*)&sV[vt * 16 + llo][kc * 32 + lhi * 8];
      oacc[vt] = MFMA16(pa, vb, oacc[vt]);
    }
  }

  // write fp32 output
#pragma unroll
  for (int vt = 0; vt < 8; ++vt) {
#pragma unroll
    for (int r = 0; r < 4; ++r) {
      int qq = q0w + lhi * 4 + r;
      if (qq < T_) out[((size_t)b * T_ + qq) * DK + vt * 16 + llo] = oacc[vt][r];
    }
  }
}

extern "C" void kernel_launch(void* const* d_in, const int* in_sizes, int n_in,
                              void* d_out, int out_size, void* d_ws, size_t ws_size,
                              hipStream_t stream) {
  const float* q    = (const float*)d_in[0];
  const int*   padm = (const int*)d_in[1];
  const float* Wq   = (const float*)d_in[2];
  const float* Wk   = (const float*)d_in[3];
  const float* Wv   = (const float*)d_in[4];
  float* out        = (float*)d_out;

  char* ws = (char*)d_ws;
  __bf16* Wcat = (__bf16*)(ws + OFF_W);
  __bf16* Qb   = (__bf16*)(ws + OFF_Q);
  __bf16* Kb   = (__bf16*)(ws + OFF_K);
  __bf16* Vtb  = (__bf16*)(ws + OFF_V);

  wconv_kernel<<<768, 256, 0, stream>>>(Wq, Wk, Wv, Wcat);
  proj_kernel<<<1200, 512, 0, stream>>>(q, Wcat, Qb, Kb, Vtb);
  attn_kernel<0><<<256, 256, 0, stream>>>(Qb, Kb, Vtb, padm, out);
  attn_kernel<1><<<256, 256, 0, stream>>>(Qb, Kb, Vtb, padm, out);
  attn_kernel<2><<<256, 256, 0, stream>>>(Qb, Kb, Vtb, padm, out);
  attn_kernel<3><<<256, 256, 0, stream>>>(Qb, Kb, Vtb, padm, out);
}